// Round 9
// baseline (14.359 us; speedup 1.0000x reference)
//
#include <hip/hip_runtime.h>
#include <hip/hip_bf16.h>

// TEBD_39384850104987: 6-layer coupling flow.
// s,t are univariate in the pair's scalar x0 (W1 is (L,1,H)).
// Round 9: split-N build. W2 L2 traffic = 6*256KB*(128/nodesPerWG)
// (column-slicing is traffic-free). 8 nodes/WG x 4 col-slices ->
// 384 WGs, 24 MB total W2 traffic (~0.7us), VALU spread over all CUs
// (~0.64us). Each WG owns ALL 256 k for its 64-col slice (tanh needs the
// full k-sum; s,t are linear in n so per-slice partials are legal);
// apply's staging sums the 4 slice-partials (no atomics, no zeroing).

#define BATCH  2048
#define NBITS  256
#define HID    256
#define NNODE  128
#define NSLICE 4
#define TX0    (-24.0f)
#define TH     0.375f
#define TSCALE (8.0f / 3.0f)        // 1/TH
#define FCLAMP 126.0f               // idx <= 126, idx+1 <= 127

typedef __attribute__((ext_vector_type(4))) float f32x4;

__device__ __forceinline__ float fast_tanh(float x) {
    // tanh(x) = 1 - 2/(e^{2x}+1); saturates correctly.
    float e = __expf(2.0f * x);
    return 1.0f - __fdividef(2.0f, e + 1.0f);
}

// ---------------------------------------------------------------------------
// Split-N table build: one 256-thread WG per (layer, 8-node block, 64-col
// slice). Grid 6*16*4 = 384.
//   h1 phase : thread t owns k=t; 8 tanh -> h1[k][0..7] (b128-pair store)
//   K loop   : wave wv owns k in [wv*64,+64); lane owns col c0+lane.
//              Scalar W2 load (256 B/wave-instr, line-aligned), h1 read
//              wave-uniform (broadcast, ~free), 8 scalar FMA per kk.
//   combine  : sum 4 k-quarter partials from LDS (all k now in), +b2,
//              tanh, dot W3 -> per-(node,col) s,t; half-wave butterfly
//              reduce over the 64 cols; write per-slice partial to ws.
// ---------------------------------------------------------------------------
__global__ __launch_bounds__(256, 8) void build_table(
    const float* __restrict__ W1, const float* __restrict__ b1,
    const float* __restrict__ W2, const float* __restrict__ b2,
    const float* __restrict__ W3, const float* __restrict__ b3,
    float2* __restrict__ tabp)                      // [NSLICE][6*NNODE]
{
    __shared__ __align__(16) float h1[HID][8];      // 8 KB [k][node]
    __shared__ __align__(16) float part[4][8][64];  // 8 KB [kq][node][col]

    const int t    = threadIdx.x;
    const int bid  = blockIdx.x;
    const int lane = t & 63;
    const int wv   = t >> 6;                        // 0..3 = k-quarter

    const int l   = bid >> 6;                       // layer (64 WGs each)
    const int nbk = (bid >> 2) & 15;                // node-block (8 nodes)
    const int sl  = bid & 3;                        // col-slice
    const int np  = nbk * 8;
    const int c0  = sl * 64;

    // -------- h1: thread t owns k = t, all 8 nodes --------------------------
    {
        const float w  = W1[l * HID + t];
        const float bb = b1[l * HID + t];
        float hv[8];
#pragma unroll
        for (int r = 0; r < 8; ++r)
            hv[r] = fast_tanh(fmaf(TX0 + (float)(np + r) * TH, w, bb));
        *(f32x4*)&h1[t][0] = f32x4{hv[0], hv[1], hv[2], hv[3]};
        *(f32x4*)&h1[t][4] = f32x4{hv[4], hv[5], hv[6], hv[7]};
    }
    __syncthreads();

    // -------- K loop: wave = k-quarter, lane = col --------------------------
    float acc[8];
#pragma unroll
    for (int r = 0; r < 8; ++r) acc[r] = 0.0f;
    const float* __restrict__ wp =
        W2 + (size_t)l * HID * HID + (size_t)(wv * 64) * HID + c0 + lane;
#pragma unroll 8
    for (int kk = 0; kk < 64; ++kk) {
        float w = wp[(size_t)kk * HID];             // 256 B/wave, line-aligned
        const int k = wv * 64 + kk;
        f32x4 ha = *(const f32x4*)&h1[k][0];        // wave-uniform broadcast
        f32x4 hb = *(const f32x4*)&h1[k][4];
        acc[0] = fmaf(ha[0], w, acc[0]);
        acc[1] = fmaf(ha[1], w, acc[1]);
        acc[2] = fmaf(ha[2], w, acc[2]);
        acc[3] = fmaf(ha[3], w, acc[3]);
        acc[4] = fmaf(hb[0], w, acc[4]);
        acc[5] = fmaf(hb[1], w, acc[5]);
        acc[6] = fmaf(hb[2], w, acc[6]);
        acc[7] = fmaf(hb[3], w, acc[7]);
    }
#pragma unroll
    for (int r = 0; r < 8; ++r) part[wv][r][lane] = acc[r];
    __syncthreads();

    // -------- combine: thread owns (node r = t>>5, cols c, c+32) ------------
    {
        const int r = t >> 5;                       // 0..7
        const int c = t & 31;                       // + c+32
        const int n0 = c0 + c, n1 = c0 + c + 32;
        float s, tt;
        {
            float v0 = part[0][r][c] + part[1][r][c]
                     + part[2][r][c] + part[3][r][c] + b2[l * HID + n0];
            float v1 = part[0][r][c + 32] + part[1][r][c + 32]
                     + part[2][r][c + 32] + part[3][r][c + 32] + b2[l * HID + n1];
            float h20 = fast_tanh(v0), h21 = fast_tanh(v1);
            const float2 w30 = *(const float2*)(W3 + (size_t)(l * HID + n0) * 2);
            const float2 w31 = *(const float2*)(W3 + (size_t)(l * HID + n1) * 2);
            s  = h20 * w30.x + h21 * w31.x;
            tt = h20 * w30.y + h21 * w31.y;
        }
        // butterfly over the 32 lanes sharing node r (offsets stay in half-wave)
#pragma unroll
        for (int off = 16; off >= 1; off >>= 1) {
            s  += __shfl_xor(s,  off, 64);
            tt += __shfl_xor(tt, off, 64);
        }
        if (c == 0) {
            // slice partial; b3 added once by slice 0
            float bs = (sl == 0) ? b3[l * 2 + 0] : 0.0f;
            float bt = (sl == 0) ? b3[l * 2 + 1] : 0.0f;
            tabp[sl * (6 * NNODE) + l * NNODE + np + r] =
                make_float2(s + bs, tt + bt);
        }
    }
}

// ---------------------------------------------------------------------------
// Apply: one row (256 floats) per wave; lane q owns x[4q..4q+3] as a float4.
// Even layer: pairs (v.x,v.y),(v.z,v.w) lane-local. Odd layer: pair (v.y,v.z)
// local; pair (x[4q+3], x[4q+4]) -> lane q+1 pulls x0 via shfl rotate
// (wraps 255->0). x0 operands are never written in the same layer, so no
// ordering hazard. x is prefetched into registers BEFORE the LUT staging.
// Staging sums the 4 build slice-partials (12 extra MB chip-wide L2, ~0.1us).
// ---------------------------------------------------------------------------
__global__ __launch_bounds__(256) void apply_layers(
    const float* __restrict__ Xin, float* __restrict__ Xout,
    const float2* __restrict__ tabp)
{
    __shared__ float2 lt[6 * NNODE];                // 6 KB
    const int t    = threadIdx.x;
    const int lane = t & 63;
    const int row  = blockIdx.x * 4 + (t >> 6);

    // prefetch x first: independent of LDS staging, hides HBM latency
    float4 v = *(const float4*)(Xin + (size_t)row * NBITS + lane * 4);

#pragma unroll
    for (int i = 0; i < 3; ++i) {
        const int idx = i * 256 + t;
        float2 a = tabp[idx];
        float2 b = tabp[768 + idx];
        float2 c = tabp[1536 + idx];
        float2 d = tabp[2304 + idx];
        lt[idx] = make_float2(a.x + b.x + c.x + d.x,
                              a.y + b.y + c.y + d.y);
    }
    __syncthreads();

    auto lut = [&](int l, float x0, float& s, float& tt) {
        float f = fminf(fmaxf((x0 - TX0) * TSCALE, 0.0f), FCLAMP);
        int   idx = (int)f;
        float fr  = f - (float)idx;
        float2 a = lt[l * NNODE + idx];
        float2 b = lt[l * NNODE + idx + 1];
        s  = fmaf(fr, b.x - a.x, a.x);
        tt = fmaf(fr, b.y - a.y, a.y);
    };

#pragma unroll
    for (int l = 0; l < 6; ++l) {
        float s, tt;
        if ((l & 1) == 0) {
            lut(l, v.x, s, tt);  v.y = fmaf(v.y, __expf(s), tt);
            lut(l, v.z, s, tt);  v.w = fmaf(v.w, __expf(s), tt);
        } else {
            lut(l, v.y, s, tt);  v.z = fmaf(v.z, __expf(s), tt);
            float x0n = __shfl(v.w, (lane + 63) & 63, 64);
            lut(l, x0n, s, tt);  v.x = fmaf(v.x, __expf(s), tt);
        }
    }

    *(float4*)(Xout + (size_t)row * NBITS + lane * 4) = v;
}

// ---------------------------------------------------------------------------
extern "C" void kernel_launch(void* const* d_in, const int* in_sizes, int n_in,
                              void* d_out, int out_size, void* d_ws, size_t ws_size,
                              hipStream_t stream)
{
    (void)in_sizes; (void)n_in; (void)out_size; (void)ws_size;
    const float* x  = (const float*)d_in[0];
    const float* W1 = (const float*)d_in[1];
    const float* b1 = (const float*)d_in[2];
    const float* W2 = (const float*)d_in[3];
    const float* b2 = (const float*)d_in[4];
    const float* W3 = (const float*)d_in[5];
    const float* b3 = (const float*)d_in[6];
    float* out = (float*)d_out;

    float2* tabp = (float2*)d_ws;             // 4 * 768 * 8 = 24576 B

    build_table<<<dim3(384), dim3(256), 0, stream>>>(W1, b1, W2, b2, W3, b3, tabp);
    apply_layers<<<dim3(BATCH / 4), dim3(256), 0, stream>>>(x, out, tabp);
}

// Round 10
// 12.958 us; speedup vs baseline: 1.1081x; 1.1081x over previous
//
#include <hip/hip_runtime.h>
#include <hip/hip_bf16.h>

// TEBD_39384850104987: 6-layer coupling flow.
// s,t are univariate in the pair's scalar x0 (W1 is (L,1,H)).
// Round 10: REVERT to round-8 (best measured, 13.04 us). Round 9's split-N
// build regressed (+1.3 us): scalar W2 loads cut bytes/VMEM-instruction 4x
// and per-XCD L2s don't share the sliced rows. Round-8 structure:
// build = single pass over W2 per WG (512 thr, 4 nodes/WG, split-K across
// 8 waves, float4-coalesced rows), apply = per-wave lerp pass.
// Remaining time is ~9.5 us of fixed 2-dispatch graph overhead (software
// grid barriers measured 30x worse in round 5; not addressable in source).

#define BATCH  2048
#define NBITS  256
#define HID    256
#define NNODE  128
#define TX0    (-24.0f)
#define TH     0.375f
#define TSCALE (8.0f / 3.0f)        // 1/TH
#define FCLAMP 126.0f               // idx <= 126, idx+1 <= 127

typedef __attribute__((ext_vector_type(4))) float f32x4;

__device__ __forceinline__ float fast_tanh(float x) {
    // tanh(x) = 1 - 2/(e^{2x}+1); saturates correctly.
    float e = __expf(2.0f * x);
    return 1.0f - __fdividef(2.0f, e + 1.0f);
}

// ---------------------------------------------------------------------------
// Table build: one 512-thread WG per (layer, 4-node block). 192 WGs.
//   h1 phase : thread (k = t&255, half = t>>8) computes 2 tanh -> h1[k][2h..]
//   K loop   : wave wv = kg owns k in [kg*32,+32); lane owns cols 4*n4..+3.
//              32 iters x 4 f32x4-FMA; W2 row read 1 KB/wave coalesced;
//              h1[k] read wave-uniform (broadcast).
//   combine  : sum 8 kg-partials from LDS, +b2, tanh, dot W3; butterfly
//              shfl over 64 lanes; cross-wave scalar reduce by thread 0.
// ---------------------------------------------------------------------------
__global__ __launch_bounds__(512, 2) void build_table(
    const float* __restrict__ W1, const float* __restrict__ b1,
    const float* __restrict__ W2, const float* __restrict__ b2,
    const float* __restrict__ W3, const float* __restrict__ b3,
    float2* __restrict__ tab)
{
    __shared__ __align__(16) float h1[HID][4];        // 4 KB  [k][node]
    __shared__ __align__(16) float part[8][4][HID];   // 32 KB [kg][node][n]
    __shared__ float red[8][2][2];                    // [wave][node-pair][s,t]

    const int t    = threadIdx.x;
    const int bid  = blockIdx.x;
    const int lane = t & 63;
    const int wv   = t >> 6;                          // 0..7

    const int l  = bid >> 5;                          // layer (32 WGs each)
    const int np = (bid & 31) * 4;                    // first node of 4

    // -------- h1: (k, half) -> 2 tanh ---------------------------------------
    {
        const int k    = t & 255;
        const int half = t >> 8;                      // 0..1 -> nodes 2h,2h+1
        const float w  = W1[l * HID + k];
        const float bb = b1[l * HID + k];
        float2 h;
        h.x = fast_tanh(fmaf(TX0 + (float)(np + half * 2)     * TH, w, bb));
        h.y = fast_tanh(fmaf(TX0 + (float)(np + half * 2 + 1) * TH, w, bb));
        *(float2*)&h1[k][half * 2] = h;
    }
    __syncthreads();

    // -------- K loop: wave = K-group, lane = 4 cols --------------------------
    const int kg = wv;                                // k in [kg*32, kg*32+32)
    const int n4 = lane;                              // cols 4*n4 .. 4*n4+3
    f32x4 a0 = {0.f,0.f,0.f,0.f}, a1 = {0.f,0.f,0.f,0.f};
    f32x4 a2 = {0.f,0.f,0.f,0.f}, a3 = {0.f,0.f,0.f,0.f};
    const float* __restrict__ wp =
        W2 + (size_t)l * HID * HID + (size_t)(kg * 32) * HID + n4 * 4;
#pragma unroll 8
    for (int kk = 0; kk < 32; ++kk) {
        f32x4 w4 = *(const f32x4*)(wp + (size_t)kk * HID);
        f32x4 hh = *(const f32x4*)&h1[kg * 32 + kk][0];   // wave-uniform bcast
        a0 += hh[0] * w4;
        a1 += hh[1] * w4;
        a2 += hh[2] * w4;
        a3 += hh[3] * w4;
    }
    *(f32x4*)&part[kg][0][n4 * 4] = a0;               // 1 KB contiguous/wave
    *(f32x4*)&part[kg][1][n4 * 4] = a1;
    *(f32x4*)&part[kg][2][n4 * 4] = a2;
    *(f32x4*)&part[kg][3][n4 * 4] = a3;
    __syncthreads();

    // -------- combine: thread owns (n = t&255, node pair r0 = (t>>8)*2) -----
    {
        const int n  = t & 255;
        const int r0 = (t >> 8) * 2;                  // nodes r0, r0+1
        const float  b2v = b2[l * HID + n];
        const float2 w3  = *(const float2*)(W3 + (size_t)(l * HID + n) * 2);
        float sA, tA, sB, tB;
        {
            float v = part[0][r0][n] + part[1][r0][n] + part[2][r0][n]
                    + part[3][r0][n] + part[4][r0][n] + part[5][r0][n]
                    + part[6][r0][n] + part[7][r0][n] + b2v;
            float h2 = fast_tanh(v);
            sA = h2 * w3.x;  tA = h2 * w3.y;
        }
        {
            const int r1 = r0 + 1;
            float v = part[0][r1][n] + part[1][r1][n] + part[2][r1][n]
                    + part[3][r1][n] + part[4][r1][n] + part[5][r1][n]
                    + part[6][r1][n] + part[7][r1][n] + b2v;
            float h2 = fast_tanh(v);
            sB = h2 * w3.x;  tB = h2 * w3.y;
        }
#pragma unroll
        for (int off = 32; off >= 1; off >>= 1) {
            sA += __shfl_xor(sA, off, 64);
            tA += __shfl_xor(tA, off, 64);
            sB += __shfl_xor(sB, off, 64);
            tB += __shfl_xor(tB, off, 64);
        }
        if (lane == 0) {
            // wave wv covers n in [(wv&3)*64,+64), node pair (wv>>2)
            red[wv][0][0] = sA;  red[wv][0][1] = tA;  // node r0   part
            red[wv][1][0] = sB;  red[wv][1][1] = tB;  // node r0+1 part
        }
    }
    __syncthreads();

    // -------- final: 4 nodes, sum the 4 n-quarter partials -------------------
    if (t == 0) {
        const float b3s = b3[l * 2 + 0];
        const float b3t = b3[l * 2 + 1];
#pragma unroll
        for (int r = 0; r < 4; ++r) {
            const int wbase = (r >> 1) * 4;           // waves covering node r
            const int rp    = r & 1;
            float s  = red[wbase + 0][rp][0] + red[wbase + 1][rp][0]
                     + red[wbase + 2][rp][0] + red[wbase + 3][rp][0] + b3s;
            float tt = red[wbase + 0][rp][1] + red[wbase + 1][rp][1]
                     + red[wbase + 2][rp][1] + red[wbase + 3][rp][1] + b3t;
            tab[l * NNODE + np + r] = make_float2(s, tt);
        }
    }
}

// ---------------------------------------------------------------------------
// Apply: one row (256 floats) per wave; lane q owns x[4q..4q+3] as a float4.
// Even layer: pairs (v.x,v.y),(v.z,v.w) lane-local. Odd layer: pair (v.y,v.z)
// local; pair (x[4q+3], x[4q+4]) -> lane q+1 pulls x0 via shfl rotate
// (wraps 255->0). x0 operands are never written in the same layer, so no
// ordering hazard. x is prefetched into registers BEFORE the LUT staging so
// its HBM latency hides under the staging + barrier. Table (6 KB) in LDS.
// ---------------------------------------------------------------------------
__global__ __launch_bounds__(256) void apply_layers(
    const float* __restrict__ Xin, float* __restrict__ Xout,
    const float2* __restrict__ tab)
{
    __shared__ float2 lt[6 * NNODE];                  // 6 KB
    const int t    = threadIdx.x;
    const int lane = t & 63;
    const int row  = blockIdx.x * 4 + (t >> 6);

    // prefetch x first: independent of LDS staging, hides HBM latency
    float4 v = *(const float4*)(Xin + (size_t)row * NBITS + lane * 4);

#pragma unroll
    for (int i = 0; i < 3; ++i) lt[i * 256 + t] = tab[i * 256 + t];
    __syncthreads();

    auto lut = [&](int l, float x0, float& s, float& tt) {
        float f = fminf(fmaxf((x0 - TX0) * TSCALE, 0.0f), FCLAMP);
        int   idx = (int)f;
        float fr  = f - (float)idx;
        float2 a = lt[l * NNODE + idx];
        float2 b = lt[l * NNODE + idx + 1];
        s  = fmaf(fr, b.x - a.x, a.x);
        tt = fmaf(fr, b.y - a.y, a.y);
    };

#pragma unroll
    for (int l = 0; l < 6; ++l) {
        float s, tt;
        if ((l & 1) == 0) {
            lut(l, v.x, s, tt);  v.y = fmaf(v.y, __expf(s), tt);
            lut(l, v.z, s, tt);  v.w = fmaf(v.w, __expf(s), tt);
        } else {
            lut(l, v.y, s, tt);  v.z = fmaf(v.z, __expf(s), tt);
            float x0n = __shfl(v.w, (lane + 63) & 63, 64);
            lut(l, x0n, s, tt);  v.x = fmaf(v.x, __expf(s), tt);
        }
    }

    *(float4*)(Xout + (size_t)row * NBITS + lane * 4) = v;
}

// ---------------------------------------------------------------------------
extern "C" void kernel_launch(void* const* d_in, const int* in_sizes, int n_in,
                              void* d_out, int out_size, void* d_ws, size_t ws_size,
                              hipStream_t stream)
{
    (void)in_sizes; (void)n_in; (void)out_size; (void)ws_size;
    const float* x  = (const float*)d_in[0];
    const float* W1 = (const float*)d_in[1];
    const float* b1 = (const float*)d_in[2];
    const float* W2 = (const float*)d_in[3];
    const float* b2 = (const float*)d_in[4];
    const float* W3 = (const float*)d_in[5];
    const float* b3 = (const float*)d_in[6];
    float* out = (float*)d_out;

    float2* tab = (float2*)d_ws;              // 6*128*8 = 6144 B

    build_table<<<dim3(192), dim3(512), 0, stream>>>(W1, b1, W2, b2, W3, b3, tab);
    apply_layers<<<dim3(BATCH / 4), dim3(256), 0, stream>>>(x, out, tab);
}